// Round 5
// baseline (2811.292 us; speedup 1.0000x reference)
//
#include <hip/hip_runtime.h>
#include <cstdint>
#include <cstddef>

#define B_   2
#define N_   8192
#define M_   2048
#define K_   32
#define C0_  64
#define C1_  128
#define C2_  256
#define CIN_ 67

// Exact-match distance: reference computes sum((a-b)**2, axis=-1) in f32 as
// ((dx^2 + dy^2) + dz^2) with no FMA contraction. _rn intrinsics forbid
// contract-fast fma fusion (would flip argmax / radius-boundary decisions).
__device__ __forceinline__ float sqdist_rn(float ax, float ay, float az,
                                           float bx, float by, float bz) {
  float dx = __fsub_rn(ax, bx);
  float dy = __fsub_rn(ay, by);
  float dz = __fsub_rn(az, bz);
  return __fadd_rn(__fadd_rn(__fmul_rn(dx, dx), __fmul_rn(dy, dy)),
                   __fmul_rn(dz, dz));
}

__device__ __forceinline__ int morton8(int ix, int iy, int iz) {
  int m = 0;
#pragma unroll
  for (int b = 0; b < 3; ++b) {
    m |= (((ix >> b) & 1) << (3 * b + 2)) | (((iy >> b) & 1) << (3 * b + 1)) |
         (((iz >> b) & 1) << (3 * b + 0));
  }
  return m;
}

// u64 max across the wave via paired DPP (row_shr 1/2/4/8, row_bcast 15/31);
// cumulative max lands in lane 63. bound_ctrl=false + old=self => lanes with
// no source contribute their own value (max(v,v)=v). Exact tie-break is baked
// into the key (d | inv_pid | pos), so a plain unsigned max is sufficient.
__device__ __forceinline__ unsigned long long wave_max_u64_dpp(unsigned long long k) {
#define FPS_STEP(ctrl)                                                         \
  {                                                                            \
    int klo = (int)(unsigned)k, khi = (int)(unsigned)(k >> 32);                \
    int olo = __builtin_amdgcn_update_dpp(klo, klo, ctrl, 0xf, 0xf, false);    \
    int ohi = __builtin_amdgcn_update_dpp(khi, khi, ctrl, 0xf, 0xf, false);    \
    unsigned long long ok =                                                    \
        ((unsigned long long)(unsigned)ohi << 32) | (unsigned)olo;             \
    if (ok > k) k = ok;                                                        \
  }
  FPS_STEP(0x111)  // row_shr:1
  FPS_STEP(0x112)  // row_shr:2
  FPS_STEP(0x114)  // row_shr:4
  FPS_STEP(0x118)  // row_shr:8
  FPS_STEP(0x142)  // row_bcast:15
  FPS_STEP(0x143)  // row_bcast:31
#undef FPS_STEP
  return k;
}

// ---------------------------------------------------------------------------
// 1) Furthest point sampling — 8 waves (512 thr, 2/SIMD), LDS point state,
//    2-level pruning (thread sphere -> 2 bucket spheres), FAT dirty rounds,
//    parity-buffered plain candidate slots, ONE barrier per iteration,
//    NO atomics in the loop.
//
//    R1-R4 post-mortem: the ~2700 cy/iter floor was fixed exchange machinery
//    scaling with wave count — 16-deep same-address ds_max_u64 RMW chain,
//    16x4 broadcast LDS reads for winner distribution, 16-wave barrier skew.
//    The dirty-round engine (R4 fat rounds) and pruning (R3 2-level) are
//    verified-good; this version halves the wave count (TLP=2/SIMD still
//    hides LDS latency, which R3's 1/SIMD did not) and replaces the atomic
//    winner protocol with s_cand[2][8] parity slots:
//      iter it (p=it&1): read s_cand[p][lane&7] -> 3-step DPP butterfly
//      (quad xor1, xor2, half-mirror) -> all lanes hold winning key; write
//      s_cand[p^1][w] (plain b64, lane 63) before next barrier.
//    Race-freedom (R3-proven pattern): write(p^1)@it and read(p^1)@it+1 are
//    separated by barrier(it+1); read(p)@it and write(p)@it+1 by the same.
//    Winner coords parked in registers (4 rows/thread); global stores only
//    at kernel end (global stores inside the loop drain vmcnt at barriers).
//
//    Key = (d_bits<<26) | (8191-pid)<<13 | pos : u64 max == (max d, then min
//    ORIGINAL index) == jnp.argmax first-occurrence. Skip proof (bucket): if
//    dist(win,c) > sqrt(bd*1.0001)+rad then for all pts dist(win,pt) >=
//    dist-rad > sqrt(bd) >= sqrt(d[k]) -> fmin no-op, key unchanged. Same
//    inequality at thread level with (cT, radT, max bucket bd). Margins
//    (1.0001, 1.00002, +1e-12) dwarf ulps. Updates are exact fmin ->
//    order-free. All arithmetic identical to the passing R2/R4 kernels.
// ---------------------------------------------------------------------------
__global__ __launch_bounds__(512, 2) void fps_kernel(const float* __restrict__ xyz,
                                                     float* __restrict__ new_xyz) {
  const int b = blockIdx.x;
  const int t = threadIdx.x;    // 0..511
  const int lane = t & 63;
  const int w = t >> 6;         // 0..7
  const float* xb = xyz + (size_t)b * N_ * 3;

  __shared__ __align__(16) float s_px[N_];          // 32 KiB sorted x
  __shared__ __align__(16) float s_py[N_];          // 32 KiB sorted y
  __shared__ __align__(16) float s_pz[N_];          // 32 KiB sorted z
  __shared__ __align__(16) float s_d[N_];           // 32 KiB min dists (sort scratch union)
  __shared__ __align__(16) unsigned short s_pid[N_];// 16 KiB original ids
  __shared__ __align__(16) unsigned long long s_bkey[N_ / 8]; // 8 KiB bucket keys
  __shared__ int s_wlist[8][128];                   //  4 KiB per-wave dirty lists
  __shared__ unsigned long long s_cand[2][8];       // parity-buffered candidates

  int* hist = (int*)s_d;        // sort scratch aliases s_d (dead until init)
  int* boff = hist + 512;
  int* wsum = boff + 512;

  // ---- counting sort by morton cell (SoA + u16 pid) ----
  hist[t] = 0;
  __syncthreads();
#pragma unroll 4
  for (int rr = 0; rr < 16; ++rr) {
    int i = rr * 512 + t;
    float X = xb[i * 3 + 0], Y = xb[i * 3 + 1], Z = xb[i * 3 + 2];
    int ix = min(7, max(0, (int)(X * 8.0f)));
    int iy = min(7, max(0, (int)(Y * 8.0f)));
    int iz = min(7, max(0, (int)(Z * 8.0f)));
    atomicAdd(&hist[morton8(ix, iy, iz)], 1);
  }
  __syncthreads();
  // exclusive scan of 512 bins (8 waves, 1 bin/thread)
  {
    int ov = hist[t];
    int v = ov;
#pragma unroll
    for (int off = 1; off < 64; off <<= 1) {
      int n = __shfl_up(v, off);
      if (lane >= off) v += n;
    }
    if (lane == 63) wsum[w] = v;
    __syncthreads();
    if (t == 0) {
      int acc = 0;
#pragma unroll
      for (int j = 0; j < 8; ++j) { int x0 = wsum[j]; wsum[j] = acc; acc += x0; }
    }
    __syncthreads();
    boff[t] = v - ov + wsum[w];
  }
  __syncthreads();
#pragma unroll 4
  for (int rr = 0; rr < 16; ++rr) {
    int i = rr * 512 + t;
    float X = xb[i * 3 + 0], Y = xb[i * 3 + 1], Z = xb[i * 3 + 2];
    int ix = min(7, max(0, (int)(X * 8.0f)));
    int iy = min(7, max(0, (int)(Y * 8.0f)));
    int iz = min(7, max(0, (int)(Z * 8.0f)));
    int pos = atomicAdd(&boff[morton8(ix, iy, iz)], 1);
    s_px[pos] = X; s_py[pos] = Y; s_pz[pos] = Z;
    s_pid[pos] = (unsigned short)i;
  }
  __syncthreads();  // sort done; hist/boff scratch (in s_d) dead below

  // ---- per-thread init: 2 buckets (centroid, rad, key) + thread sphere ----
  float csx[2], csy[2], csz[2], rads[2], thrs[2];
  unsigned long long ks[2];
  float cTx = 0.f, cTy = 0.f, cTz = 0.f;
#pragma unroll
  for (int s = 0; s < 2; ++s) {
    int base = t * 16 + s * 8;
    float sx = 0.f, sy = 0.f, sz = 0.f;
#pragma unroll
    for (int j = 0; j < 8; ++j) { sx += s_px[base + j]; sy += s_py[base + j]; sz += s_pz[base + j]; }
    csx[s] = sx * 0.125f; csy[s] = sy * 0.125f; csz[s] = sz * 0.125f;
    cTx += sx; cTy += sy; cTz += sz;
  }
  cTx *= (1.f / 16.f); cTy *= (1.f / 16.f); cTz *= (1.f / 16.f);
  float r2T = 0.f;
#pragma unroll
  for (int s = 0; s < 2; ++s) {
    int base = t * 16 + s * 8;
    float r2 = 0.f; unsigned mlk = 0;
#pragma unroll
    for (int j = 0; j < 8; ++j) {
      int p2 = base + j;
      float X = s_px[p2], Y = s_py[p2], Z = s_pz[p2];
      float dx = X - csx[s], dy = Y - csy[s], dz = Z - csz[s];
      r2 = fmaxf(r2, dx * dx + dy * dy + dz * dz);
      float tx = X - cTx, ty = Y - cTy, tz = Z - cTz;
      r2T = fmaxf(r2T, tx * tx + ty * ty + tz * tz);
      unsigned pid = s_pid[p2];
      unsigned lk = ((8191u - pid) << 13) | (unsigned)p2;
      mlk = lk > mlk ? lk : mlk;
      s_d[p2] = 1e10f;  // == f32(10000000000.0), matches jnp init exactly
    }
    rads[s] = sqrtf(r2) * 1.00002f + 1e-12f;
    ks[s] = ((unsigned long long)(unsigned)__float_as_int(1e10f) << 26) | mlk;
    thrs[s] = 3e38f;  // never skip until first update
    s_bkey[2 * t + s] = ks[s];
  }
  const float radT = sqrtf(r2T) * 1.00002f + 1e-12f;
  float thrT = 3e38f;

  unsigned long long tmax = (ks[0] > ks[1]) ? ks[0] : ks[1];
  unsigned long long wmax = wave_max_u64_dpp(tmax);  // valid at lane 63
  if (lane == 63) s_cand[0][w] = wmax;

  // per-thread winner parking: thread t owns rows t, t+512, t+1024, t+1536
  float a0x = 0.f, a0y = 0.f, a0z = 0.f, a1x = 0.f, a1y = 0.f, a1z = 0.f;
  float a2x = 0.f, a2y = 0.f, a2z = 0.f, a3x = 0.f, a3y = 0.f, a3z = 0.f;

  for (int it = 0; it < M_; ++it) {
    __syncthreads();  // ONLY barrier this iteration
    const int p = it & 1;
    unsigned long long ck = s_cand[p][lane & 7];  // 8-slot ds_read_b64
#define Q_STEP(ctrl)                                                           \
    {                                                                          \
      int klo = (int)(unsigned)ck, khi = (int)(unsigned)(ck >> 32);            \
      int olo = __builtin_amdgcn_update_dpp(klo, klo, ctrl, 0xf, 0xf, false);  \
      int ohi = __builtin_amdgcn_update_dpp(khi, khi, ctrl, 0xf, 0xf, false);  \
      unsigned long long ok =                                                  \
          ((unsigned long long)(unsigned)ohi << 32) | (unsigned)olo;           \
      if (ok > ck) ck = ok;                                                    \
    }
    Q_STEP(0xB1)   // quad_perm [1,0,3,2]  (xor 1)
    Q_STEP(0x4E)   // quad_perm [2,3,0,1]  (xor 2)
    Q_STEP(0x141)  // row_half_mirror: combines the two quads of each 8
#undef Q_STEP
    const int winPos = (int)(unsigned)ck & 8191;
    const float lx = s_px[winPos], ly = s_py[winPos], lz = s_pz[winPos];
    if (it == t)        { a0x = lx; a0y = ly; a0z = lz; }
    if (it == 512 + t)  { a1x = lx; a1y = ly; a1z = lz; }
    if (it == 1024 + t) { a2x = lx; a2y = ly; a2z = lz; }
    if (it == 1536 + t) { a3x = lx; a3y = ly; a3z = lz; }

    // ---- thread-sphere skip test ----
    float ex = lx - cTx, ey = ly - cTy, ez = lz - cTz;
    float dc2T = ex * ex + ey * ey + ez * ez;
    bool dirtyT = dc2T <= thrT;
    if (__ballot(dirtyT) != 0ull) {
      bool dB0 = false, dB1 = false;
      int cnt = 0;
#define BTEST(s, dBs)                                                          \
      {                                                                        \
        bool db = false;                                                       \
        if (dirtyT) {                                                          \
          float bx_ = lx - csx[s], by_ = ly - csy[s], bz_ = lz - csz[s];       \
          db = (bx_ * bx_ + by_ * by_ + bz_ * bz_) <= thrs[s];                 \
        }                                                                      \
        unsigned long long ms = __ballot(db);                                  \
        if (db) {                                                              \
          int pn = cnt + __popcll(ms & ((1ull << lane) - 1ull));               \
          s_wlist[w][pn] = 2 * t + (s);                                        \
        }                                                                      \
        cnt += __popcll(ms);                                                   \
        dBs = db;                                                              \
      }
      BTEST(0, dB0) BTEST(1, dB1)
#undef BTEST
      if (cnt > 0) {  // wave-uniform
        asm volatile("s_waitcnt lgkmcnt(0)" ::: "memory");
        // FAT rounds: 32 buckets/round, 2 lanes/bucket, 4 pts/lane, b128 LDS.
        int rounds = (cnt + 31) >> 5;
        for (int r = 0; r < rounds; ++r) {
          int gi = r * 32 + (lane >> 1);
          bool act = gi < cnt;
          int bkt = s_wlist[w][act ? gi : 0];
          int pb = bkt * 8 + (lane & 1) * 4;
          float4 X4 = *(const float4*)&s_px[pb];
          float4 Y4 = *(const float4*)&s_py[pb];
          float4 Z4 = *(const float4*)&s_pz[pb];
          float4 D4 = *(float4*)&s_d[pb];
          ushort4 P4 = *(const ushort4*)&s_pid[pb];
          unsigned long long bk = 0ull;
#define UPD(Xc, Yc, Zc, Dc, Pc, off)                                           \
          {                                                                    \
            float dist = sqdist_rn(Xc, Yc, Zc, lx, ly, lz);                    \
            float dm = fminf(Dc, dist); /* exact min: order-free, skip-safe */ \
            Dc = dm;                                                           \
            unsigned long long key =                                           \
                ((unsigned long long)(unsigned)__float_as_int(dm) << 26) |     \
                (((8191u - (unsigned)(Pc)) << 13) | (unsigned)(pb + (off)));   \
            if (key > bk) bk = key;                                            \
          }
          UPD(X4.x, Y4.x, Z4.x, D4.x, P4.x, 0)
          UPD(X4.y, Y4.y, Z4.y, D4.y, P4.y, 1)
          UPD(X4.z, Y4.z, Z4.z, D4.z, P4.z, 2)
          UPD(X4.w, Y4.w, Z4.w, D4.w, P4.w, 3)
#undef UPD
          if (act) *(float4*)&s_d[pb] = D4;
          // pair reduce (lanes 2i <-> 2i+1), all-VALU (quad_perm xor1)
          {
            int klo = (int)(unsigned)bk, khi = (int)(unsigned)(bk >> 32);
            int olo = __builtin_amdgcn_update_dpp(klo, klo, 0xB1, 0xf, 0xf, false);
            int ohi = __builtin_amdgcn_update_dpp(khi, khi, 0xB1, 0xf, 0xf, false);
            unsigned long long ok =
                ((unsigned long long)(unsigned)ohi << 32) | (unsigned)olo;
            if (ok > bk) bk = ok;
          }
          if (act && !(lane & 1)) s_bkey[bkt] = bk;
        }
        asm volatile("s_waitcnt lgkmcnt(0)" ::: "memory");
        // owner re-reads both bucket keys with one b128 (adjacent, aligned)
        {
          unsigned long long k0 = s_bkey[2 * t];
          unsigned long long k1 = s_bkey[2 * t + 1];
          if (dB0) {
            ks[0] = k0;
            float bd = __int_as_float((int)(unsigned)(k0 >> 26));
            float sr = sqrtf(bd * 1.0001f) + rads[0];
            thrs[0] = sr * sr;
          }
          if (dB1) {
            ks[1] = k1;
            float bd = __int_as_float((int)(unsigned)(k1 >> 26));
            float sr = sqrtf(bd * 1.0001f) + rads[1];
            thrs[1] = sr * sr;
          }
        }
        tmax = (ks[0] > ks[1]) ? ks[0] : ks[1];
        if (dB0 | dB1) {
          float bdT = __int_as_float((int)(unsigned)(tmax >> 26));
          float srT = sqrtf(bdT * 1.0001f) + radT;
          thrT = srT * srT;
        }
        wmax = wave_max_u64_dpp(tmax);
      }
    }
    if (lane == 63) s_cand[p ^ 1][w] = wmax;  // plain b64 write, no atomic
  }

  // ---- dump winners straight from registers (dense across the block) ----
  {
    float* dst = new_xyz + (size_t)b * M_ * 3;
    dst[t * 3 + 0] = a0x; dst[t * 3 + 1] = a0y; dst[t * 3 + 2] = a0z;
    dst[(512 + t) * 3 + 0] = a1x; dst[(512 + t) * 3 + 1] = a1y; dst[(512 + t) * 3 + 2] = a1z;
    dst[(1024 + t) * 3 + 0] = a2x; dst[(1024 + t) * 3 + 1] = a2y; dst[(1024 + t) * 3 + 2] = a2z;
    dst[(1536 + t) * 3 + 0] = a3x; dst[(1536 + t) * 3 + 1] = a3y; dst[(1536 + t) * 3 + 2] = a3z;
  }
}

// ---------------------------------------------------------------------------
// 2) Fused ball-query + grouping + MLP(67->128 relu ->256) + max over K.
//    One block (256 thr) per centroid. Ball query: wave w scans index chunk
//    [w*2048,(w+1)*2048) in order, ballot-appends first <=32 valid to its own
//    LDS list; lists concat in wave order == global index order (pointnet2
//    first-K semantics). Writes pre-BN pooled features TRANSPOSED into the
//    final (B,C2,M) output region (no scratch needed).
// ---------------------------------------------------------------------------
__global__ __launch_bounds__(256) void mlp_kernel(const float* __restrict__ xyz,
                                                  const float* __restrict__ x,
                                                  const float* __restrict__ W1,
                                                  const float* __restrict__ b1,
                                                  const float* __restrict__ W2,
                                                  const float* __restrict__ b2,
                                                  const float* __restrict__ new_xyz,
                                                  float* __restrict__ outp) {
  __shared__ float sGRed[32 * 69];   // group tile; unioned w/ 8x256 max-red
  __shared__ float sU[128 * 69];     // W1 staged; unioned w/ 32x256 W2 tile
  __shared__ float sH1[32 * 132];
  __shared__ int sWIdx[4][K_];
  __shared__ int sWCnt[4];
  __shared__ int sIdx[K_];
  __shared__ float sQ[3];

  const int gm = blockIdx.x;
  const int b = gm >> 11;    // M_ = 2048
  const int m = gm & 2047;
  const int t = threadIdx.x;
  const int lane = t & 63;
  const int w = t >> 6;
  const float* xb = xyz + (size_t)b * N_ * 3;

  if (t < 3) sQ[t] = new_xyz[(size_t)gm * 3 + t];
  __syncthreads();
  const float qx = sQ[0], qy = sQ[1], qz = sQ[2];
  // (float)(0.1*0.1) = 0x3C23D70A; 0.1f*0.1f rounds differently — wrong.
  const float R2 = (float)(0.1 * 0.1);

  // ---- ball query ----
  {
    int cnt = 0;
    const int cbeg = w * 2048, cend = cbeg + 2048;
    for (int base = cbeg; base < cend; base += 64) {
      int p = base + lane;
      float d2 = sqdist_rn(qx, qy, qz, xb[p * 3 + 0], xb[p * 3 + 1], xb[p * 3 + 2]);
      bool valid = d2 < R2;
      unsigned long long mask = __ballot(valid);
      if (valid) {
        int pos = cnt + __popcll(mask & ((1ull << lane) - 1ull));
        if (pos < K_) sWIdx[w][pos] = p;
      }
      cnt += __popcll(mask);
      if (cnt >= K_) break;  // wave-uniform
    }
    if (lane == 0) sWCnt[w] = (cnt < K_) ? cnt : K_;
  }
  __syncthreads();
  if (t < K_) {
    int c0 = sWCnt[0], c1 = sWCnt[1], c2 = sWCnt[2], c3 = sWCnt[3];
    int s1 = c0 + c1, s2 = s1 + c2, s3 = s2 + c3;
    int j = t, idx;
    if (j < c0) idx = sWIdx[0][j];
    else if (j < s1) idx = sWIdx[1][j - c0];
    else if (j < s2) idx = sWIdx[2][j - s1];
    else if (j < s3) idx = sWIdx[3][j - s2];
    else {
      int fw = c0 ? 0 : (c1 ? 1 : (c2 ? 2 : 3));
      idx = (s3 > 0) ? sWIdx[fw][0] : 0;  // fill with first valid index
    }
    sIdx[j] = idx;
  }
  __syncthreads();

  // ---- grouping: rel coords + features into sGRed (32 x 69 padded) ----
  if (t < K_) {
    int id = sIdx[t];
    sGRed[t * 69 + 0] = xb[id * 3 + 0] - qx;
    sGRed[t * 69 + 1] = xb[id * 3 + 1] - qy;
    sGRed[t * 69 + 2] = xb[id * 3 + 2] - qz;
  }
  {
    int r = t & 31;
    int c0 = (t >> 5) * 8;
    int id = sIdx[r];
    const float* xf = x + ((size_t)b * C0_ + c0) * N_ + id;
#pragma unroll
    for (int j = 0; j < 8; ++j) sGRed[r * 69 + 3 + c0 + j] = xf[(size_t)j * N_];
  }
  for (int i = t; i < C1_ * CIN_; i += 256) {
    sU[(i / CIN_) * 69 + (i % CIN_)] = W1[i];
  }
  __syncthreads();

  const int ol = t & 31;  // output-lane: o = ol + 32*j
  const int rg = t >> 5;  // row group: rows rg*4 .. rg*4+3

  // ---- layer 1: h1 = relu(G @ W1^T + b1), 4 rows x 4 outs per thread ----
  float acc[4][4] = {{0.f}};
  for (int c = 0; c < CIN_; ++c) {
    float g[4], wv[4];
#pragma unroll
    for (int i = 0; i < 4; ++i) g[i] = sGRed[(rg * 4 + i) * 69 + c];
#pragma unroll
    for (int j = 0; j < 4; ++j) wv[j] = sU[(ol + 32 * j) * 69 + c];
#pragma unroll
    for (int i = 0; i < 4; ++i)
#pragma unroll
      for (int j = 0; j < 4; ++j) acc[i][j] += g[i] * wv[j];
  }
#pragma unroll
  for (int j = 0; j < 4; ++j) {
    float bias = b1[ol + 32 * j];
#pragma unroll
    for (int i = 0; i < 4; ++i) {
      float v = acc[i][j] + bias;
      sH1[(rg * 4 + i) * 132 + ol + 32 * j] = fmaxf(v, 0.0f);
    }
  }

  // ---- layer 2: h2 = h1 @ W2^T, 4 rows x 8 outs per thread ----
  float acc2[4][8] = {{0.f}};
  for (int ct = 0; ct < 4; ++ct) {
    __syncthreads();  // sU reuse safe; (ct==0) also covers sH1 writes
    const float4* w4 = (const float4*)(W2 + (size_t)t * C1_ + ct * 32);
#pragma unroll
    for (int jj = 0; jj < 8; ++jj) {
      float4 v = w4[jj];
      sU[(jj * 4 + 0) * 256 + t] = v.x;
      sU[(jj * 4 + 1) * 256 + t] = v.y;
      sU[(jj * 4 + 2) * 256 + t] = v.z;
      sU[(jj * 4 + 3) * 256 + t] = v.w;
    }
    __syncthreads();
    for (int cc = 0; cc < 32; ++cc) {
      float h[4], wv[8];
#pragma unroll
      for (int i = 0; i < 4; ++i) h[i] = sH1[(rg * 4 + i) * 132 + ct * 32 + cc];
#pragma unroll
      for (int j = 0; j < 8; ++j) wv[j] = sU[cc * 256 + ol + 32 * j];
#pragma unroll
      for (int i = 0; i < 4; ++i)
#pragma unroll
        for (int j = 0; j < 8; ++j) acc2[i][j] += h[i] * wv[j];
    }
  }

  // ---- max over K, + b2 (max(x)+c == max(x+c): RN is monotone) ----
  __syncthreads();  // group tile dead; reuse sGRed as reduction buffer
#pragma unroll
  for (int j = 0; j < 8; ++j) {
    float pm = acc2[0][j];
#pragma unroll
    for (int i = 1; i < 4; ++i) pm = fmaxf(pm, acc2[i][j]);
    sGRed[rg * 256 + ol + 32 * j] = pm;
  }
  __syncthreads();
  {
    int o = t;
    float v = sGRed[o];
#pragma unroll
    for (int g = 1; g < 8; ++g) v = fmaxf(v, sGRed[g * 256 + o]);
    v += b2[o];
    // transposed store into final (B, C2, M) layout (pre-BN)
    outp[((size_t)(b * C2_ + o)) * M_ + m] = v;
  }
}

// ---------------------------------------------------------------------------
// 3) BN stats per channel (deterministic, double accum). One block / channel.
// ---------------------------------------------------------------------------
__global__ __launch_bounds__(256) void bn_stats_kernel(const float* __restrict__ outp,
                                                       const float* __restrict__ gamma,
                                                       float* __restrict__ stats) {
  const int o = blockIdx.x;
  const int t = threadIdx.x;
  double s = 0.0, s2 = 0.0;
  for (int b = 0; b < B_; ++b) {
    const float* p = outp + ((size_t)(b * C2_ + o)) * M_;
    for (int i = t; i < M_; i += 256) {
      float v = p[i];
      s += (double)v;
      s2 += (double)v * (double)v;
    }
  }
#pragma unroll
  for (int off = 32; off > 0; off >>= 1) {
    s += __shfl_xor(s, off);
    s2 += __shfl_xor(s2, off);
  }
  __shared__ double aS[4], aS2[4];
  if ((t & 63) == 0) { aS[t >> 6] = s; aS2[t >> 6] = s2; }
  __syncthreads();
  if (t == 0) {
    double S = aS[0] + aS[1] + aS[2] + aS[3];
    double S2 = aS2[0] + aS2[1] + aS2[2] + aS2[3];
    double mean = S / (double)(B_ * M_);
    double var = S2 / (double)(B_ * M_) - mean * mean;
    float rstd = 1.0f / sqrtf((float)var + 1e-5f);
    stats[o] = (float)mean;
    stats[C2_ + o] = gamma[o] * rstd;
  }
}

// ---------------------------------------------------------------------------
// 4) BN apply, in place on the (B,C2,M) output region. float4-vectorized.
// ---------------------------------------------------------------------------
__global__ __launch_bounds__(256) void bn_apply_kernel(float* __restrict__ outp,
                                                       const float* __restrict__ stats,
                                                       const float* __restrict__ beta) {
  const int i4 = blockIdx.x * 256 + threadIdx.x;  // B_*C2_*M_/4 = 262144
  const int ch = (i4 >> 9) & 255;                 // M_/4 = 512 float4 / chan
  const float mean = stats[ch];
  const float scale = stats[C2_ + ch];
  const float bt = beta[ch];
  float4 v = ((const float4*)outp)[i4];
  v.x = (v.x - mean) * scale + bt;
  v.y = (v.y - mean) * scale + bt;
  v.z = (v.z - mean) * scale + bt;
  v.w = (v.w - mean) * scale + bt;
  ((float4*)outp)[i4] = v;
}

// ---------------------------------------------------------------------------
extern "C" void kernel_launch(void* const* d_in, const int* in_sizes, int n_in,
                              void* d_out, int out_size, void* d_ws, size_t ws_size,
                              hipStream_t stream) {
  const float* xyz   = (const float*)d_in[0];
  const float* x     = (const float*)d_in[1];
  const float* W1    = (const float*)d_in[2];
  const float* b1    = (const float*)d_in[3];
  const float* W2    = (const float*)d_in[4];
  const float* b2    = (const float*)d_in[5];
  const float* gamma = (const float*)d_in[6];
  const float* beta  = (const float*)d_in[7];

  float* new_xyz = (float*)d_out;                       // (B, M, 3)
  float* outp    = (float*)d_out + (size_t)B_ * M_ * 3; // (B, C2, M)
  float* stats   = (float*)d_ws;                        // 2*C2 floats = 2 KB

  fps_kernel<<<B_, 512, 0, stream>>>(xyz, new_xyz);
  mlp_kernel<<<B_ * M_, 256, 0, stream>>>(xyz, x, W1, b1, W2, b2, new_xyz, outp);
  bn_stats_kernel<<<C2_, 256, 0, stream>>>(outp, gamma, stats);
  bn_apply_kernel<<<(B_ * C2_ * M_ / 4) / 256, 256, 0, stream>>>(outp, stats, beta);
}